// Round 2
// 1699.869 us; speedup vs baseline: 1.5864x; 1.5864x over previous
//
#include <hip/hip_runtime.h>
#include <hip/hip_bf16.h>

typedef __bf16 bfr;
typedef bfr v8bf __attribute__((ext_vector_type(8)));
typedef bfr v4bf __attribute__((ext_vector_type(4)));
typedef float v4f __attribute__((ext_vector_type(4)));

static constexpr int Bn = 64, H = 256, D = 768;
static constexpr int NR = 100000, ER = 400000;
static constexpr int NC = 100000, EC = 300000, G = 512;
static constexpr int SCAN_CH = 1024;  // elements per scan block

// ---------------- utility ----------------
__global__ void fill_f32(float* p, float v, int n) {
  int i = blockIdx.x * blockDim.x + threadIdx.x;
  if (i < n) p[i] = v;
}
__global__ void fill_i32(int* p, int v, int n) {
  int i = blockIdx.x * blockDim.x + threadIdx.x;
  if (i < n) p[i] = v;
}

// W f32 [K,N] -> Wt bf16 [N,K]
__global__ void transpose_w(const float* __restrict__ W, bfr* __restrict__ Wt,
                            int K, int N) {
  int i = blockIdx.x * blockDim.x + threadIdx.x;
  if (i >= K * N) return;
  int k = i / N, n = i - k * N;
  Wt[(size_t)n * K + k] = (bfr)W[i];
}

// ---------------- small GEMM (M=64 modality projections only) ----------------
// mfma_f32_16x16x32_bf16: A[m=lane&15][k=quad*8+j]; B[k=quad*8+j][n=lane&15];
// D[row=quad*4+r][col=lane&15]   (m89/m91-verified layouts)
template<typename TA>
__launch_bounds__(256)
__global__ void gemm_k(const TA* __restrict__ A, const bfr* __restrict__ Bt,
                       bfr* __restrict__ Cb, float* __restrict__ Cf,
                       int M, int K, int ldc, int col0) {
  int wid = (int)((blockIdx.x * 256u + threadIdx.x) >> 6);
  int m0 = wid * 16;
  if (m0 >= M) return;
  int lane = threadIdx.x & 63;
  int mrow = lane & 15;
  int quad = lane >> 4;
  const TA* Ap = A + (size_t)(m0 + mrow) * K + quad * 8;
  const bfr* Bp = Bt + (size_t)mrow * K + quad * 8;
  v4f acc[16] = {};
  for (int k0 = 0; k0 < K; k0 += 32) {
    v8bf a;
    if constexpr (sizeof(TA) == 4) {
      const float4* p = (const float4*)(Ap + k0);
      float4 x = p[0], y = p[1];
      a[0] = (bfr)x.x; a[1] = (bfr)x.y; a[2] = (bfr)x.z; a[3] = (bfr)x.w;
      a[4] = (bfr)y.x; a[5] = (bfr)y.y; a[6] = (bfr)y.z; a[7] = (bfr)y.w;
    } else {
      a = *(const v8bf*)(Ap + k0);
    }
#pragma unroll
    for (int nt = 0; nt < 16; ++nt) {
      v8bf b = *(const v8bf*)(Bp + (size_t)nt * 16 * K + k0);
      acc[nt] = __builtin_amdgcn_mfma_f32_16x16x32_bf16(a, b, acc[nt], 0, 0, 0);
    }
  }
#pragma unroll
  for (int nt = 0; nt < 16; ++nt) {
#pragma unroll
    for (int r = 0; r < 4; ++r) {
      int row = m0 + quad * 4 + r;
      int col = col0 + nt * 16 + mrow;
      float v = acc[nt][r];
      if (Cf) Cf[(size_t)row * ldc + col] = v;
      else    Cb[(size_t)row * ldc + col] = (bfr)v;
    }
  }
}

// ---------------- tiled GEMM for the big matrices (N fixed = 256) ----------
// BM=128, BN=256 (full output width -> A read exactly once), BK=32.
// 512 threads = 8 waves arranged 2(M) x 4(N); each wave owns 64x64 = 4x4
// fragments of 16x16x32 MFMA. LDS staged via global_load_lds width 16
// (bf16 A) or reg-stage + cvt (f32 A). Linear LDS (m97 structure).
static constexpr int TBM = 128, TBN = 256, TBK = 32;

__device__ __forceinline__ void gld_lds16(const void* g, void* l) {
  __builtin_amdgcn_global_load_lds(
      (const __attribute__((address_space(1))) void*)g,
      (__attribute__((address_space(3))) void*)l, 16, 0, 0);
}

template<typename TA>
__launch_bounds__(512)
__global__ void gemm_tile(const TA* __restrict__ A, const bfr* __restrict__ Bt,
                          bfr* __restrict__ C, int M, int K) {
  __shared__ bfr As[TBM * TBK];  // 8 KB, row-major [128][32]
  __shared__ bfr Bs[TBN * TBK];  // 16 KB, row-major [256][32] (rows = out cols)
  int m0 = blockIdx.x * TBM;
  int t = threadIdx.x;
  int lane = t & 63;
  int w = t >> 6;           // wave 0..7
  int wm = w >> 2;          // 0..1
  int wn = w & 3;           // 0..3
  int mrow = lane & 15;
  int quad = lane >> 4;

  // ---- staging addresses (chunk = 16B = 8 bf16 elements) ----
  // A: 512 chunks, 1 round. chunk c=t -> row c>>2, col-chunk c&3.
  int rA = t >> 2, ccA = t & 3;
  int rgA = m0 + rA; if (rgA >= M) rgA = M - 1;  // clamp tail tile (read-only)
  const TA* gA = A + (size_t)rgA * K + ccA * 8;
  // B: 1024 chunks, 2 rounds. round j: chunk c=j*512+t.
  int rB0 = t >> 2, ccB = t & 3;
  const bfr* gB0 = Bt + (size_t)rB0 * K + ccB * 8;
  const bfr* gB1 = Bt + (size_t)(128 + rB0) * K + ccB * 8;
  // LDS dests: wave-uniform base; HW adds lane*16.
  bfr* lA  = As + (size_t)(w * 64) * 8;
  bfr* lB0 = Bs + (size_t)(w * 64) * 8;
  bfr* lB1 = Bs + (size_t)(512 + w * 64) * 8;

  // ---- fragment read bases ----
  const bfr* pA = As + (size_t)(wm * 64 + mrow) * TBK + quad * 8;
  const bfr* pB = Bs + (size_t)(wn * 64 + mrow) * TBK + quad * 8;

  v4f acc[4][4] = {};
  for (int k0 = 0; k0 < K; k0 += TBK) {
    if constexpr (sizeof(TA) == 2) {
      gld_lds16(gA, lA);
    } else {
      const float4* p = (const float4*)gA;
      float4 x = p[0], y = p[1];
      v8bf v;
      v[0] = (bfr)x.x; v[1] = (bfr)x.y; v[2] = (bfr)x.z; v[3] = (bfr)x.w;
      v[4] = (bfr)y.x; v[5] = (bfr)y.y; v[6] = (bfr)y.z; v[7] = (bfr)y.w;
      *(v8bf*)(As + (size_t)t * 8) = v;
    }
    gld_lds16(gB0, lB0);
    gld_lds16(gB1, lB1);
    gA += TBK; gB0 += TBK; gB1 += TBK;
    __syncthreads();  // drains vmcnt (gld_lds) + lgkmcnt (ds_write)

    v8bf af[4], bfv[4];
#pragma unroll
    for (int i = 0; i < 4; ++i)
      af[i] = *(const v8bf*)(pA + (size_t)i * 16 * TBK);
#pragma unroll
    for (int i = 0; i < 4; ++i)
      bfv[i] = *(const v8bf*)(pB + (size_t)i * 16 * TBK);
#pragma unroll
    for (int mi = 0; mi < 4; ++mi)
#pragma unroll
      for (int ni = 0; ni < 4; ++ni)
        acc[mi][ni] = __builtin_amdgcn_mfma_f32_16x16x32_bf16(
            af[mi], bfv[ni], acc[mi][ni], 0, 0, 0);
    __syncthreads();  // protect LDS before next stage
  }

#pragma unroll
  for (int mi = 0; mi < 4; ++mi) {
#pragma unroll
    for (int ni = 0; ni < 4; ++ni) {
#pragma unroll
      for (int r = 0; r < 4; ++r) {
        int row = m0 + wm * 64 + mi * 16 + quad * 4 + r;
        int col = wn * 64 + ni * 16 + mrow;
        if (row < M) C[(size_t)row * H + col] = (bfr)acc[mi][ni][r];
      }
    }
  }
}

// ---------------- CSR build ----------------
__global__ void deg_count_i(const int* __restrict__ dst, int* deg, int E) {
  int e = blockIdx.x * blockDim.x + threadIdx.x;
  if (e < E) atomicAdd(deg + dst[e], 1);
}
__global__ void dinv_from_deg(const int* __restrict__ deg, float* dinv, int n) {
  int i = blockIdx.x * blockDim.x + threadIdx.x;
  if (i < n) dinv[i] = rsqrtf((float)deg[i] + 1.0f);  // +1 self loop
}

// hierarchical exclusive scan: deg[n] -> part[n] (chunk-local), bsum per block
__global__ void scan1(const int* __restrict__ deg, int* __restrict__ part,
                      int* __restrict__ bsum, int n) {
  __shared__ int tmp[256];
  int t = threadIdx.x;
  int base = blockIdx.x * SCAN_CH + t * 4;
  int v0 = (base + 0 < n) ? deg[base + 0] : 0;
  int v1 = (base + 1 < n) ? deg[base + 1] : 0;
  int v2 = (base + 2 < n) ? deg[base + 2] : 0;
  int v3 = (base + 3 < n) ? deg[base + 3] : 0;
  int ls = v0 + v1 + v2 + v3;
  tmp[t] = ls;
  __syncthreads();
  for (int o = 1; o < 256; o <<= 1) {
    int vv = (t >= o) ? tmp[t - o] : 0;
    __syncthreads();
    tmp[t] += vv;
    __syncthreads();
  }
  int off = tmp[t] - ls;  // exclusive prefix of this thread's group
  if (base + 0 < n) part[base + 0] = off;
  if (base + 1 < n) part[base + 1] = off + v0;
  if (base + 2 < n) part[base + 2] = off + v0 + v1;
  if (base + 3 < n) part[base + 3] = off + v0 + v1 + v2;
  if (t == 255) bsum[blockIdx.x] = tmp[255];
}
__global__ void scan2(int* bsum, int nb) {  // in-place exclusive
  if (threadIdx.x == 0 && blockIdx.x == 0) {
    int run = 0;
    for (int b = 0; b < nb; ++b) { int s = bsum[b]; bsum[b] = run; run += s; }
  }
}
__global__ void scan3(int* __restrict__ part, const int* __restrict__ bsum,
                      int n, int E) {
  int i = blockIdx.x * blockDim.x + threadIdx.x;
  if (i < n) part[i] += bsum[i / SCAN_CH];
  if (i == n) part[n] = E;
}

__global__ void fill_edges(const int* __restrict__ src, const int* __restrict__ dst,
                           const float* __restrict__ dinv, const int* __restrict__ rp,
                           int* __restrict__ cursor, int* __restrict__ esrc,
                           float* __restrict__ ew, int E) {
  int e = blockIdx.x * blockDim.x + threadIdx.x;
  if (e >= E) return;
  int s = src[e], d = dst[e];
  int pos = rp[d] + atomicAdd(cursor + d, 1);
  esrc[pos] = s;
  ew[pos] = dinv[s] * dinv[d];
}

// ---------------- GCN aggregate (gather, no atomics) ----------------
// one wave per node; lane owns cols [lane*4, lane*4+4)
__device__ __forceinline__ void bf4_to_f32(const ushort4 u, float f[4]) {
  f[0] = __uint_as_float((unsigned)u.x << 16);
  f[1] = __uint_as_float((unsigned)u.y << 16);
  f[2] = __uint_as_float((unsigned)u.z << 16);
  f[3] = __uint_as_float((unsigned)u.w << 16);
}
template<bool RELU>
__launch_bounds__(256)
__global__ void gcn_gather(const bfr* __restrict__ h, const int* __restrict__ rp,
                           const int* __restrict__ esrc, const float* __restrict__ ew,
                           const float* __restrict__ dinv,
                           bfr* __restrict__ outB, float* __restrict__ outF, int N) {
  int node = (int)((blockIdx.x * 256u + threadIdx.x) >> 6);
  if (node >= N) return;
  int lane = threadIdx.x & 63;
  const ushort* hp = (const ushort*)h;
  size_t self = (size_t)node * H + lane * 4;
  float di = dinv[node];
  float w0 = di * di;
  float a[4], f[4];
  bf4_to_f32(*(const ushort4*)(hp + self), f);
  a[0] = f[0] * w0; a[1] = f[1] * w0; a[2] = f[2] * w0; a[3] = f[3] * w0;
  int beg = rp[node], end = rp[node + 1];
  for (int j = beg; j < end; ++j) {
    int s = esrc[j];
    float wj = ew[j];
    bf4_to_f32(*(const ushort4*)(hp + (size_t)s * H + lane * 4), f);
    a[0] += f[0] * wj; a[1] += f[1] * wj; a[2] += f[2] * wj; a[3] += f[3] * wj;
  }
  if (RELU) {
    v4bf o;
    o[0] = (bfr)fmaxf(a[0], 0.0f); o[1] = (bfr)fmaxf(a[1], 0.0f);
    o[2] = (bfr)fmaxf(a[2], 0.0f); o[3] = (bfr)fmaxf(a[3], 0.0f);
    *(v4bf*)(outB + self) = o;
  } else {
    float4 o = make_float4(a[0], a[1], a[2], a[3]);
    *(float4*)(outF + self) = o;
  }
}

// ---------------- pooling: sorted seg -> block per segment, no atomics ----
__global__ void pool_seg(const float* __restrict__ x, const int* __restrict__ seg,
                         int n, float* __restrict__ out, int ldo, int col0) {
  int s = blockIdx.x;
  int t = threadIdx.x;
  int lo = 0, hi = n;
  while (lo < hi) { int m = (lo + hi) >> 1; if (seg[m] < s) lo = m + 1; else hi = m; }
  int beg = lo;
  hi = n;
  while (lo < hi) { int m = (lo + hi) >> 1; if (seg[m] < s + 1) lo = m + 1; else hi = m; }
  int end = lo;
  float a0 = 0, a1 = 0, a2 = 0, a3 = 0;
  int r = beg;
  for (; r + 4 <= end; r += 4) {
    a0 += x[(size_t)(r + 0) * H + t];
    a1 += x[(size_t)(r + 1) * H + t];
    a2 += x[(size_t)(r + 2) * H + t];
    a3 += x[(size_t)(r + 3) * H + t];
  }
  for (; r < end; ++r) a0 += x[(size_t)r * H + t];
  float acc = (a0 + a1) + (a2 + a3);
  out[(size_t)s * ldo + col0 + t] = acc / fmaxf((float)(end - beg), 1.0f);
}

// ---------------- head ----------------
__launch_bounds__(256)
__global__ void final_mlp(const float* __restrict__ reps, const float* __restrict__ W1,
                          const float* __restrict__ b1, const float* __restrict__ W2,
                          const float* __restrict__ b2, const int* __restrict__ label,
                          float* __restrict__ out, float* __restrict__ loss_acc) {
  __shared__ float r[5 * H];
  __shared__ float h[H];
  __shared__ float pr[2];
  int b = blockIdx.x;
  int t = threadIdx.x;
  for (int i = t; i < 5 * H; i += 256) r[i] = reps[(size_t)b * (5 * H) + i];
  __syncthreads();
  float acc = b1[t];
  for (int k = 0; k < 5 * H; ++k) acc += r[k] * W1[(size_t)k * H + t];
  h[t] = fmaxf(acc, 0.0f);
  __syncthreads();
  if (t < 2) {
    float p = b2[t];
    for (int k = 0; k < H; ++k) p += h[k] * W2[k * 2 + t];
    pr[t] = p;
  }
  __syncthreads();
  if (t == 0) {
    float p0 = pr[0], p1 = pr[1];
    out[b * 2 + 0] = p0;
    out[b * 2 + 1] = p1;
    float m = fmaxf(p0, p1);
    float lse = m + logf(expf(p0 - m) + expf(p1 - m));
    float lp = (label[b] ? p1 : p0) - lse;
    atomicAdd(loss_acc, -lp * (1.0f / 64.0f));
  }
}
__global__ void loss_write(const float* loss_acc, float* out) {
  out[128] = *loss_acc;
}

// ---------------- host ----------------
extern "C" void kernel_launch(void* const* d_in, const int* in_sizes, int n_in,
                              void* d_out, int out_size, void* d_ws, size_t ws_size,
                              hipStream_t stream) {
  const float* content   = (const float*)d_in[0];
  const float* video     = (const float*)d_in[1];
  const float* image     = (const float*)d_in[2];
  const float* repost_x  = (const float*)d_in[3];
  const float* comment_x = (const float*)d_in[4];
  const float* W_text    = (const float*)d_in[5];
  const float* W_video   = (const float*)d_in[6];
  const float* W_image   = (const float*)d_in[7];
  const float* Wr1       = (const float*)d_in[8];
  const float* Wr2       = (const float*)d_in[9];
  const float* Wc1       = (const float*)d_in[10];
  const float* Wc2       = (const float*)d_in[11];
  const float* W1        = (const float*)d_in[12];
  const float* b1        = (const float*)d_in[13];
  const float* W2        = (const float*)d_in[14];
  const float* b2        = (const float*)d_in[15];
  const int* r_edge      = (const int*)d_in[16];
  const int* r_batch     = (const int*)d_in[17];
  const int* c_edge      = (const int*)d_in[18];
  const int* c_batch     = (const int*)d_in[19];
  const int* cg_batch    = (const int*)d_in[20];
  const int* label       = (const int*)d_in[21];
  float* out = (float*)d_out;

  char* wsb = (char*)d_ws;
  size_t off = 0;
  auto alloc = [&](size_t bytes) -> void* {
    void* p = wsb + off;
    off += (bytes + 255) & ~(size_t)255;
    return p;
  };
  const size_t NH = (size_t)NR * H;  // == NC*H
  bfr*   bufA    = (bfr*)alloc(NH * 2);
  bfr*   bufB    = (bfr*)alloc(NH * 2);
  float* bufC    = (float*)alloc(NH * 4);
  float* dinv    = (float*)alloc(NR * 4);
  int*   deg     = (int*)alloc(NR * 4);
  int*   cursor  = (int*)alloc(NR * 4);
  int*   row_ptr = (int*)alloc((NR + 1) * 4);
  int*   esrc    = (int*)alloc((size_t)ER * 4);
  float* ew      = (float*)alloc((size_t)ER * 4);
  int*   bsum    = (int*)alloc(128 * 4);
  bfr*   Wt_t    = (bfr*)alloc((size_t)D * H * 2);
  bfr*   Wt_v    = (bfr*)alloc((size_t)D * H * 2);
  bfr*   Wt_i    = (bfr*)alloc((size_t)D * H * 2);
  bfr*   Wt_r1   = (bfr*)alloc((size_t)H * H * 2);
  bfr*   Wt_r2   = (bfr*)alloc((size_t)H * H * 2);
  bfr*   Wt_c1   = (bfr*)alloc((size_t)H * H * 2);
  bfr*   Wt_c2   = (bfr*)alloc((size_t)H * H * 2);
  float* reps    = (float*)alloc((size_t)Bn * 5 * H * 4);
  float* graphs  = (float*)alloc((size_t)G * H * 4);
  float* lossw   = (float*)alloc(4);
  (void)ws_size; (void)n_in; (void)in_sizes; (void)out_size;

  const int T = 256;
  auto cdiv = [](int a, int b) { return (a + b - 1) / b; };

  transpose_w<<<cdiv(D * H, T), T, 0, stream>>>(W_text, Wt_t, D, H);
  transpose_w<<<cdiv(D * H, T), T, 0, stream>>>(W_video, Wt_v, D, H);
  transpose_w<<<cdiv(D * H, T), T, 0, stream>>>(W_image, Wt_i, D, H);
  transpose_w<<<cdiv(H * H, T), T, 0, stream>>>(Wr1, Wt_r1, H, H);
  transpose_w<<<cdiv(H * H, T), T, 0, stream>>>(Wr2, Wt_r2, H, H);
  transpose_w<<<cdiv(H * H, T), T, 0, stream>>>(Wc1, Wt_c1, H, H);
  transpose_w<<<cdiv(H * H, T), T, 0, stream>>>(Wc2, Wt_c2, H, H);
  fill_f32<<<1, 1, 0, stream>>>(lossw, 0.0f, 1);

  // tiny modality GEMMs (M=64) keep the per-wave path, writing f32 into reps
  auto gemm_small = [&](const float* A, const bfr* Bt, float* Cf,
                        int M, int K, int ldc, int col0) {
    gemm_k<float><<<cdiv(M / 16, 4), T, 0, stream>>>(A, Bt, nullptr, Cf, M, K, ldc, col0);
  };
  // big tiled GEMMs (N=256)
  auto gemm_big_f = [&](const float* A, const bfr* Bt, bfr* C, int M, int K) {
    gemm_tile<float><<<cdiv(M, TBM), 512, 0, stream>>>(A, Bt, C, M, K);
  };
  auto gemm_big_b = [&](const bfr* A, const bfr* Bt, bfr* C, int M, int K) {
    gemm_tile<bfr><<<cdiv(M, TBM), 512, 0, stream>>>(A, Bt, C, M, K);
  };
  auto build_csr = [&](const int* edge, int N, int E) {
    int nb = cdiv(N, SCAN_CH);
    fill_i32<<<cdiv(N, T), T, 0, stream>>>(deg, 0, N);
    deg_count_i<<<cdiv(E, T), T, 0, stream>>>(edge + E, deg, E);
    dinv_from_deg<<<cdiv(N, T), T, 0, stream>>>(deg, dinv, N);
    scan1<<<nb, T, 0, stream>>>(deg, row_ptr, bsum, N);
    scan2<<<1, 64, 0, stream>>>(bsum, nb);
    scan3<<<cdiv(N + 1, T), T, 0, stream>>>(row_ptr, bsum, N, E);
    fill_i32<<<cdiv(N, T), T, 0, stream>>>(cursor, 0, N);
    fill_edges<<<cdiv(E, T), T, 0, stream>>>(edge, edge + E, dinv, row_ptr,
                                             cursor, esrc, ew, E);
  };
  auto gather_relu = [&](const bfr* h, bfr* o, int N) {
    gcn_gather<true><<<cdiv(N, 4), T, 0, stream>>>(h, row_ptr, esrc, ew, dinv,
                                                   o, nullptr, N);
  };
  auto gather_f32 = [&](const bfr* h, float* o, int N) {
    gcn_gather<false><<<cdiv(N, 4), T, 0, stream>>>(h, row_ptr, esrc, ew, dinv,
                                                    nullptr, o, N);
  };

  // modality GEMMs straight into reps
  gemm_small(content, Wt_t, reps, Bn, D, 5 * H, 0 * H);
  gemm_small(video,   Wt_v, reps, Bn, D, 5 * H, 3 * H);
  gemm_small(image,   Wt_i, reps, Bn, D, 5 * H, 4 * H);

  // ---- repost branch ----
  gemm_big_f(repost_x, Wt_t, bufA, NR, D);
  build_csr(r_edge, NR, ER);
  gemm_big_b(bufA, Wt_r1, bufB, NR, H);
  gather_relu(bufB, bufA, NR);
  gemm_big_b(bufA, Wt_r2, bufB, NR, H);
  gather_f32(bufB, bufC, NR);
  pool_seg<<<Bn, H, 0, stream>>>(bufC, r_batch, NR, reps, 5 * H, 1 * H);

  // ---- comment branch ----
  gemm_big_f(comment_x, Wt_t, bufA, NC, D);
  build_csr(c_edge, NC, EC);
  gemm_big_b(bufA, Wt_c1, bufB, NC, H);
  gather_relu(bufB, bufA, NC);
  gemm_big_b(bufA, Wt_c2, bufB, NC, H);
  gather_f32(bufB, bufC, NC);
  pool_seg<<<G, H, 0, stream>>>(bufC, c_batch, NC, graphs, H, 0);
  pool_seg<<<Bn, H, 0, stream>>>(graphs, cg_batch, G, reps, 5 * H, 2 * H);

  // ---- head ----
  final_mlp<<<Bn, T, 0, stream>>>(reps, W1, b1, W2, b2, label, out, lossw);
  loss_write<<<1, 1, 0, stream>>>(lossw, out);
}